// Round 8
// baseline (427.799 us; speedup 1.0000x reference)
//
#include <hip/hip_runtime.h>

#define Bn 4
#define Cn 256
#define Tn 4096

typedef unsigned short u16;
typedef __bf16 bf16x8 __attribute__((ext_vector_type(8)));
typedef float f32x4 __attribute__((ext_vector_type(4)));
typedef float f32x16 __attribute__((ext_vector_type(16)));
typedef u16 u16x8 __attribute__((ext_vector_type(8)));

__device__ __forceinline__ float b2f(u16 u) {
    union { unsigned int i; float f; } v;
    v.i = ((unsigned int)u) << 16;
    return v.f;
}
__device__ __forceinline__ u16 f2b(float f) {
    union { float f; unsigned int i; } v;
    v.f = f;
    unsigned int r = v.i + 0x7FFFu + ((v.i >> 16) & 1u);
    return (u16)(r >> 16);
}
__device__ __forceinline__ bf16x8 ones8() {
    union { u16 u[8]; bf16x8 v; } t;
    for (int j = 0; j < 8; j++) t.u[j] = 0x3F80;  // bf16 1.0
    return t.v;
}

// ---------------------------------------------------------------------------
// Weight convert: five fp32 [C][C] weights -> contiguous bf16 regions in ws.
// Region 1 (Wq) is pre-scaled by 1/16 (attention scale folded into q-proj).
// ---------------------------------------------------------------------------
__global__ __launch_bounds__(256) void cvt_kernel(
    const float* __restrict__ w0, const float* __restrict__ w1,
    const float* __restrict__ w2, const float* __restrict__ w3,
    const float* __restrict__ w4, u16* __restrict__ dst)
{
    int gid = blockIdx.x * 256 + threadIdx.x;
    int base = gid * 4;
    int region = base >> 16;
    int off = base & 65535;
    const float* src = region == 0 ? w0 : region == 1 ? w1
                     : region == 2 ? w2 : region == 3 ? w3 : w4;
    float sc = (region == 1) ? 0.0625f : 1.0f;
    float4 v = *(const float4*)(src + off);
    ushort4 o;
    o.x = f2b(v.x * sc); o.y = f2b(v.y * sc);
    o.z = f2b(v.z * sc); o.w = f2b(v.w * sc);
    *(ushort4*)(dst + base) = o;
}

// ---------------------------------------------------------------------------
// LN: h = x*m (f32 stats), ln = (h-mu)*rsqrt(var+eps)*gamma+beta -> lnT
// [B][T][C] bf16. 32 t-rows/block -> 512 blocks.
// ---------------------------------------------------------------------------
__global__ __launch_bounds__(256) void ln_kernel(
    const float* __restrict__ x, const float* __restrict__ mask,
    const float* __restrict__ gamma, const float* __restrict__ beta,
    u16* __restrict__ lnT)
{
    __shared__ __attribute__((aligned(16))) u16 tile[32][264];
    __shared__ float ssum[8][32], ssq[8][32], smu[32], srs[32];
    const int tid = threadIdx.x;
    const int b = blockIdx.y;
    const int t0 = blockIdx.x * 32;
    const int g = tid >> 5, tl = tid & 31;
    const int t = t0 + tl;
    const float mval = mask[b * Tn + t];
    float s = 0.f, s2 = 0.f;
    for (int c = g; c < Cn; c += 8) {
        float v = x[((size_t)(b * Cn + c)) * Tn + t] * mval;
        s += v; s2 += v * v;
        tile[tl][c] = f2b(v);
    }
    ssum[g][tl] = s; ssq[g][tl] = s2;
    __syncthreads();
    if (tid < 32) {
        float su = 0.f, sq = 0.f;
        for (int k = 0; k < 8; k++) { su += ssum[k][tid]; sq += ssq[k][tid]; }
        float mu = su * (1.f / Cn);
        float var = sq * (1.f / Cn) - mu * mu;
        var = fmaxf(var, 0.0f);
        smu[tid] = mu;
        srs[tid] = 1.0f / sqrtf(var + 1e-5f);
    }
    __syncthreads();
    for (int it = 0; it < 4; it++) {
        int idx = it * 256 + tid;
        int row = idx >> 5, c16 = idx & 31;
        float mu = smu[row], rs = srs[row];
        u16x8 ov;
        for (int j = 0; j < 8; j++) {
            int c = c16 * 8 + j;
            float h = b2f(tile[row][c]);
            float v = (h - mu) * rs * gamma[c] + beta[c];
            ov[j] = f2b(v);
        }
        *(u16x8*)(lnT + ((size_t)(b * Tn + t0 + row)) * Cn + c16 * 8) = ov;
    }
}

// ---------------------------------------------------------------------------
// Wp GEMM: Y[t][o] = sum_c A[t][c] * W[o][c], epilogue (acc+bias)*mask -> bf16
// ---------------------------------------------------------------------------
__global__ __launch_bounds__(256) void wp_kernel(
    const u16* __restrict__ Xb, const u16* __restrict__ Wb,
    const float* __restrict__ bias, const float* __restrict__ mask,
    u16* __restrict__ Yout)
{
    __shared__ __attribute__((aligned(16))) u16 Al[128][72];
    __shared__ __attribute__((aligned(16))) u16 Bl[64][72];
    const int tid = threadIdx.x;
    const int b = blockIdx.z;
    const int m0 = blockIdx.x * 128;
    const int n0 = blockIdx.y * 64;
    const int wave = tid >> 6, lane = tid & 63;
    const int ln16 = lane & 15, quad = lane >> 4;
    const int wm = (wave & 1) * 64, wn = (wave >> 1) * 32;

    const u16* Abase = Xb + ((size_t)(b * Tn + m0)) * Cn;
    const u16* Bbase = Wb + (size_t)n0 * Cn;

    f32x4 acc[4][2];
    for (int i = 0; i < 4; i++)
        for (int j = 0; j < 2; j++) acc[i][j] = (f32x4){0.f, 0.f, 0.f, 0.f};

    for (int k0 = 0; k0 < Cn; k0 += 64) {
        for (int it = 0; it < 4; it++) {
            int idx = it * 256 + tid;
            int row = idx >> 3, gg = idx & 7;
            *(uint4*)(&Al[row][gg * 8]) =
                *(const uint4*)(Abase + (size_t)row * Cn + k0 + gg * 8);
        }
        for (int it = 0; it < 2; it++) {
            int idx = it * 256 + tid;
            int row = idx >> 3, gg = idx & 7;
            *(uint4*)(&Bl[row][gg * 8]) =
                *(const uint4*)(Bbase + (size_t)row * Cn + k0 + gg * 8);
        }
        __syncthreads();
        for (int kk = 0; kk < 2; kk++) {
            bf16x8 af[4], bfr[2];
            for (int i = 0; i < 4; i++)
                af[i] = *(const bf16x8*)(&Al[wm + i * 16 + ln16][kk * 32 + quad * 8]);
            for (int j = 0; j < 2; j++)
                bfr[j] = *(const bf16x8*)(&Bl[wn + j * 16 + ln16][kk * 32 + quad * 8]);
            for (int i = 0; i < 4; i++)
                for (int j = 0; j < 2; j++)
                    acc[i][j] = __builtin_amdgcn_mfma_f32_16x16x32_bf16(
                        af[i], bfr[j], acc[i][j], 0, 0, 0);
        }
        __syncthreads();
    }
    for (int i = 0; i < 4; i++) {
        for (int j = 0; j < 2; j++) {
            int nn = n0 + wn + j * 16 + ln16;
            for (int r = 0; r < 4; r++) {
                int tt = m0 + wm + i * 16 + quad * 4 + r;
                float val = acc[i][j][r] + bias[nn];
                val *= mask[b * Tn + tt];
                Yout[((size_t)(b * Tn + tt)) * Cn + nn] = f2b(val);
            }
        }
    }
}

// ---------------------------------------------------------------------------
// Fused q/k/v projections. z: which=z>>2 (0=q,1=k,2=v), b=z&3. v gets an
// LDS-transpose epilogue for coalesced [C][T] store.
// ---------------------------------------------------------------------------
__global__ __launch_bounds__(256) void qkv_kernel(
    const u16* __restrict__ h1T,
    const u16* __restrict__ Wq_, const float* __restrict__ bq_,
    const u16* __restrict__ Wk_, const float* __restrict__ bk_,
    const u16* __restrict__ Wv_, const float* __restrict__ bv_,
    const float* __restrict__ mask,
    u16* __restrict__ qO, u16* __restrict__ kO, u16* __restrict__ vO)
{
    __shared__ __attribute__((aligned(16))) u16 Al[128][72];
    __shared__ __attribute__((aligned(16))) u16 Bl[64][72];
    const int tid = threadIdx.x;
    const int z = blockIdx.z;
    const int which = z >> 2;
    const int b = z & 3;
    const u16* W = which == 0 ? Wq_ : which == 1 ? Wk_ : Wv_;
    const float* bi = which == 0 ? bq_ : which == 1 ? bk_ : bv_;
    const float bsc = which == 0 ? 0.0625f : 1.0f;
    const int m0 = blockIdx.x * 128;   // t
    const int n0 = blockIdx.y * 64;    // o
    const int wave = tid >> 6, lane = tid & 63;
    const int ln16 = lane & 15, quad = lane >> 4;
    const int wm = (wave & 1) * 64, wn = (wave >> 1) * 32;

    const u16* Abase = h1T + ((size_t)(b * Tn + m0)) * Cn;
    const u16* Bbase = W + (size_t)n0 * Cn;

    f32x4 acc[4][2];
    for (int i = 0; i < 4; i++)
        for (int j = 0; j < 2; j++) acc[i][j] = (f32x4){0.f, 0.f, 0.f, 0.f};

    for (int k0 = 0; k0 < Cn; k0 += 64) {
        for (int it = 0; it < 4; it++) {
            int idx = it * 256 + tid;
            int row = idx >> 3, gg = idx & 7;
            *(uint4*)(&Al[row][gg * 8]) =
                *(const uint4*)(Abase + (size_t)row * Cn + k0 + gg * 8);
        }
        for (int it = 0; it < 2; it++) {
            int idx = it * 256 + tid;
            int row = idx >> 3, gg = idx & 7;
            *(uint4*)(&Bl[row][gg * 8]) =
                *(const uint4*)(Bbase + (size_t)row * Cn + k0 + gg * 8);
        }
        __syncthreads();
        for (int kk = 0; kk < 2; kk++) {
            bf16x8 af[4], bfr[2];
            for (int i = 0; i < 4; i++)
                af[i] = *(const bf16x8*)(&Al[wm + i * 16 + ln16][kk * 32 + quad * 8]);
            for (int j = 0; j < 2; j++)
                bfr[j] = *(const bf16x8*)(&Bl[wn + j * 16 + ln16][kk * 32 + quad * 8]);
            for (int i = 0; i < 4; i++)
                for (int j = 0; j < 2; j++)
                    acc[i][j] = __builtin_amdgcn_mfma_f32_16x16x32_bf16(
                        af[i], bfr[j], acc[i][j], 0, 0, 0);
        }
        __syncthreads();
    }

    if (which < 2) {
        u16* Yo = which == 0 ? qO : kO;
        for (int i = 0; i < 4; i++) {
            for (int j = 0; j < 2; j++) {
                int nn = n0 + wn + j * 16 + ln16;
                for (int r = 0; r < 4; r++) {
                    int tt = m0 + wm + i * 16 + quad * 4 + r;
                    float val = acc[i][j][r] + bi[nn] * bsc;
                    val *= mask[b * Tn + tt];
                    Yo[((size_t)(b * Tn + tt)) * Cn + nn] = f2b(val);
                }
            }
        }
    } else {
        u16* vt = &Al[0][0];
        for (int i = 0; i < 4; i++) {
            for (int j = 0; j < 2; j++) {
                int nl = wn + j * 16 + ln16;
                for (int r = 0; r < 4; r++) {
                    int ml = wm + i * 16 + quad * 4 + r;
                    int tt = m0 + ml;
                    float val = acc[i][j][r] + bi[n0 + nl];
                    val *= mask[b * Tn + tt];
                    vt[nl * 136 + ml] = f2b(val);
                }
            }
        }
        __syncthreads();
        for (int itc = 0; itc < 4; itc++) {
            int cidx = itc * 256 + tid;
            int row = cidx >> 4;
            int ch = cidx & 15;
            u16x8 ov = *(const u16x8*)(vt + row * 136 + ch * 8);
            *(u16x8*)(vO + ((size_t)(b * Cn + n0 + row)) * Tn + m0 + ch * 8) = ov;
        }
    }
}

// ---------------------------------------------------------------------------
// Flash attention, 512 thr = 8 waves (2/SIMD). Wave-pairing + delayed PV:
// 4 pairs x 64 q-rows. Wave (pair,sub): QK+P for its 32 rows; PV covers the
// pair's 64 rows x 128 channels (sub half), reading partner P from LDS.
// PV for iter i-1 runs in iter i's staging phase (off the critical chain,
// overlaps ds_write staging + global prefetch). vls double-buffered;
// kls/pls single (reads drain at the intervening barriers). l-accum reuses
// the already-loaded own-P fragment (zero extra DS reads). Fixed-max
// softmax (q pre-scaled 1/16, M=8 folded into negk).
// ---------------------------------------------------------------------------
__global__ __launch_bounds__(512, 2) void attn_kernel(
    const u16* __restrict__ qT, const u16* __restrict__ kT,
    const u16* __restrict__ vv, const float* __restrict__ mask,
    u16* __restrict__ PO, float* __restrict__ pL)
{
    __shared__ __attribute__((aligned(16))) u16 kls[32][264];     // [s][c]
    __shared__ __attribute__((aligned(16))) u16 vls[2][256][40];  // [c][s] x2
    __shared__ __attribute__((aligned(16))) u16 pls[8][32][40];   // per-wave P
    __shared__ float nls[1024];
    const int tid = threadIdx.x;
    const int id = blockIdx.x;
    const int spl = id & 3;
    const int b = (id >> 2) & 3;
    const int qb = id >> 4;
    const int t0 = qb * 256;
    const int wave = tid >> 6, lane = tid & 63;
    const int ln32 = lane & 31, half = lane >> 5;
    const int pair = wave >> 1, sub = wave & 1;
    const int sBeg = spl * (Tn / 4);

    for (int i = tid; i < 1024; i += 512)
        nls[i] = (1.0f - mask[b * Tn + sBeg + i]) * -1e8f - 8.0f;

    // Q fragments for own 32 rows
    bf16x8 qf[16];
    {
        const u16* qp = qT + ((size_t)(b * Tn + t0 + pair * 64 + sub * 32 + ln32)) * Cn + half * 8;
        for (int ks = 0; ks < 16; ks++) qf[ks] = *(const bf16x8*)(qp + ks * 16);
    }
    f32x16 acc[8], lac;   // acc[mt*4+nt]: rows pair*64+mt*32, ch sub*128+nt*32
    for (int i = 0; i < 16; i++) lac[i] = 0.f;
    for (int nt = 0; nt < 8; nt++) acc[nt] = lac;
    const bf16x8 ones = ones8();

    const int nIter = (Tn / 4) / 32;        // 32

    uint4 kpre[2], vpre[2];
    auto loadK = [&](int s0) {
        for (int i = 0; i < 2; i++) {
            int idx = i * 512 + tid;
            kpre[i] = *(const uint4*)(kT + ((size_t)(b * Tn + s0 + (idx >> 5))) * Cn + (idx & 31) * 8);
        }
    };
    auto loadV = [&](int s0) {
        for (int i = 0; i < 2; i++) {
            int idx = i * 512 + tid;
            vpre[i] = *(const uint4*)(vv + ((size_t)(b * Cn + (idx >> 2))) * Tn + s0 + (idx & 3) * 8);
        }
    };
    auto pv = [&](int pb) {
        bf16x8 pf[2][2];
        for (int mt = 0; mt < 2; mt++) {
            int wsrc = pair * 2 + mt;
            pf[mt][0] = *(const bf16x8*)(&pls[wsrc][ln32][half * 8]);
            pf[mt][1] = *(const bf16x8*)(&pls[wsrc][ln32][16 + half * 8]);
        }
        for (int nt = 0; nt < 4; nt++) {
            int cb = sub * 128 + nt * 32 + ln32;
            bf16x8 v0 = *(const bf16x8*)(&vls[pb][cb][half * 8]);
            bf16x8 v1 = *(const bf16x8*)(&vls[pb][cb][16 + half * 8]);
            acc[nt]     = __builtin_amdgcn_mfma_f32_32x32x16_bf16(pf[0][0], v0, acc[nt], 0, 0, 0);
            acc[nt]     = __builtin_amdgcn_mfma_f32_32x32x16_bf16(pf[0][1], v1, acc[nt], 0, 0, 0);
            acc[4 + nt] = __builtin_amdgcn_mfma_f32_32x32x16_bf16(pf[1][0], v0, acc[4 + nt], 0, 0, 0);
            acc[4 + nt] = __builtin_amdgcn_mfma_f32_32x32x16_bf16(pf[1][1], v1, acc[4 + nt], 0, 0, 0);
        }
        lac = __builtin_amdgcn_mfma_f32_32x32x16_bf16(pf[sub][0], ones, lac, 0, 0, 0);
        lac = __builtin_amdgcn_mfma_f32_32x32x16_bf16(pf[sub][1], ones, lac, 0, 0, 0);
    };

    loadK(sBeg);
    loadV(sBeg);

    for (int it = 0; it < nIter; it++) {
        const int s0 = sBeg + it * 32;
        const int cb = it & 1;
        __syncthreads();                    // B1: prev-buffer reads drained
        for (int i = 0; i < 2; i++) {
            int idx = i * 512 + tid;
            *(uint4*)(&kls[idx >> 5][(idx & 31) * 8]) = kpre[i];
        }
        for (int i = 0; i < 2; i++) {
            int idx = i * 512 + tid;
            *(uint4*)(&vls[cb][idx >> 2][(idx & 3) * 8]) = vpre[i];
        }
        if (it + 1 < nIter) {
            loadK(s0 + 32);
            loadV(s0 + 32);
        }
        if (it) pv(1 - cb);                 // delayed PV for iter it-1
        __syncthreads();                    // B2: tile published
        const float negk = nls[it * 32 + ln32];

        f32x16 S;
        for (int i = 0; i < 16; i++) S[i] = 0.f;
        for (int ks = 0; ks < 16; ks++) {
            bf16x8 kf = *(const bf16x8*)(&kls[ln32][ks * 16 + half * 8]);
            S = __builtin_amdgcn_mfma_f32_32x32x16_bf16(qf[ks], kf, S, 0, 0, 0);
        }
        for (int r = 0; r < 16; r++) S[r] = __expf(S[r] + negk);
        for (int r = 0; r < 16; r++) {
            int row = (r & 3) + 8 * (r >> 2) + 4 * half;
            pls[wave][row][ln32] = f2b(S[r]);
        }
    }
    __syncthreads();                        // partner's last P published
    pv((nIter - 1) & 1);                    // final PV

    const size_t SB = (size_t)spl * (Bn * Tn);
    for (int r = 0; r < 16; r++) {
        int trow = (r & 3) + 8 * (r >> 2) + 4 * half;
        for (int mt = 0; mt < 2; mt++) {
            int t = t0 + pair * 64 + mt * 32 + trow;
            for (int nt = 0; nt < 4; nt++)
                PO[(SB + b * Tn + t) * Cn + sub * 128 + nt * 32 + ln32] =
                    f2b(acc[mt * 4 + nt][r]);
        }
        if (ln32 == 0) {
            int t = t0 + pair * 64 + sub * 32 + trow;
            pL[SB + b * Tn + t] = lac[r];
        }
    }
}

// ---------------------------------------------------------------------------
// Final GEMM with fused split-combine: B-staging sums 4 unnormalized PO
// partials; epilogue applies 1/sum(l), bias, residual, masks -> fp32.
// ---------------------------------------------------------------------------
__global__ __launch_bounds__(256) void final_kernel(
    const u16* __restrict__ WoB, const float* __restrict__ bo,
    const u16* __restrict__ PO, const float* __restrict__ pL,
    const float* __restrict__ mask, const float* __restrict__ x,
    float* __restrict__ out)
{
    __shared__ __attribute__((aligned(16))) u16 Al[128][72];
    __shared__ __attribute__((aligned(16))) u16 Bl[64][72];
    __shared__ float rls[64];
    const int tid = threadIdx.x;
    const int b = blockIdx.z;
    const int m0 = blockIdx.x * 128;   // o
    const int n0 = blockIdx.y * 64;    // t
    const int wave = tid >> 6, lane = tid & 63;
    const int ln16 = lane & 15, quad = lane >> 4;
    const int wm = (wave & 1) * 64, wn = (wave >> 1) * 32;
    const size_t BT = (size_t)Bn * Tn;

    if (tid < 64) {
        size_t R = (size_t)b * Tn + n0 + tid;
        float l = pL[R] + pL[BT + R] + pL[2 * BT + R] + pL[3 * BT + R];
        rls[tid] = 1.0f / fmaxf(l, 1e-30f);
    }

    f32x4 acc[4][2];
    for (int i = 0; i < 4; i++)
        for (int j = 0; j < 2; j++) acc[i][j] = (f32x4){0.f, 0.f, 0.f, 0.f};

    for (int k0 = 0; k0 < Cn; k0 += 64) {
        for (int it = 0; it < 4; it++) {
            int idx = it * 256 + tid;
            int row = idx >> 3, gg = idx & 7;
            *(uint4*)(&Al[row][gg * 8]) =
                *(const uint4*)(WoB + (size_t)(m0 + row) * Cn + k0 + gg * 8);
        }
        for (int it = 0; it < 2; it++) {
            int idx = it * 256 + tid;
            int row = idx >> 3, gg = idx & 7;
            size_t base = ((size_t)b * Tn + n0 + row) * Cn + k0 + gg * 8;
            u16x8 a0 = *(const u16x8*)(PO + base);
            u16x8 a1 = *(const u16x8*)(PO + BT * Cn + base);
            u16x8 a2 = *(const u16x8*)(PO + 2 * BT * Cn + base);
            u16x8 a3 = *(const u16x8*)(PO + 3 * BT * Cn + base);
            u16x8 o;
            for (int j = 0; j < 8; j++)
                o[j] = f2b(b2f(a0[j]) + b2f(a1[j]) + b2f(a2[j]) + b2f(a3[j]));
            *(u16x8*)(&Bl[row][gg * 8]) = o;
        }
        __syncthreads();
        for (int kk = 0; kk < 2; kk++) {
            bf16x8 af[4], bfr[2];
            for (int i = 0; i < 4; i++)
                af[i] = *(const bf16x8*)(&Al[wm + i * 16 + ln16][kk * 32 + quad * 8]);
            for (int j = 0; j < 2; j++)
                bfr[j] = *(const bf16x8*)(&Bl[wn + j * 16 + ln16][kk * 32 + quad * 8]);
            for (int i = 0; i < 4; i++)
                for (int j = 0; j < 2; j++)
                    acc[i][j] = __builtin_amdgcn_mfma_f32_16x16x32_bf16(
                        af[i], bfr[j], acc[i][j], 0, 0, 0);
        }
        __syncthreads();
    }
    for (int i = 0; i < 4; i++) {
        for (int j = 0; j < 2; j++) {
            int nl = wn + j * 16 + ln16;
            int tt = n0 + nl;
            float rl = rls[nl];
            float mk = mask[b * Tn + tt];
            for (int r = 0; r < 4; r++) {
                int oo = m0 + wm + i * 16 + quad * 4 + r;
                float val = acc[i][j][r] * rl + bo[oo];
                float xr = x[((size_t)(b * Cn + oo)) * Tn + tt];
                out[((size_t)(b * Cn + oo)) * Tn + tt] = (xr + val * mk) * mk;
            }
        }
    }
}

extern "C" void kernel_launch(void* const* d_in, const int* in_sizes, int n_in,
                              void* d_out, int out_size, void* d_ws, size_t ws_size,
                              hipStream_t stream)
{
    const float* x     = (const float*)d_in[0];
    const float* xmask = (const float*)d_in[1];
    const float* gamma = (const float*)d_in[2];
    const float* beta  = (const float*)d_in[3];
    const float* Wp = (const float*)d_in[4];
    const float* bp = (const float*)d_in[5];
    const float* Wq = (const float*)d_in[6];
    const float* bq = (const float*)d_in[7];
    const float* Wk = (const float*)d_in[8];
    const float* bk = (const float*)d_in[9];
    const float* Wv = (const float*)d_in[10];
    const float* bv = (const float*)d_in[11];
    const float* Wo = (const float*)d_in[12];
    const float* bo = (const float*)d_in[13];
    float* out = (float*)d_out;

    u16* ws = (u16*)d_ws;
    const size_t SZ = (size_t)Bn * Tn * Cn;   // 4M elems
    const size_t WSZ = (size_t)Cn * Cn;
    u16* lnT = ws;            // slot0 [B][T][C]
    u16* h1T = ws + SZ;       // slot1
    u16* qTt = ws + 2 * SZ;
    u16* kTt = ws + 3 * SZ;
    u16* vB  = ws + 4 * SZ;   // [B][C][T]
    u16* wbf = ws + 5 * SZ;   // 5 bf16 weights
    u16* PO  = ws + 5 * SZ + 5 * WSZ;          // 4 x [B][T][C] bf16 partials
    float* pL = (float*)(PO + 4 * SZ);         // 4 x [B*T] f32

    u16* WpB = wbf;
    u16* WqB = wbf + WSZ;
    u16* WkB = wbf + 2 * WSZ;
    u16* WvB = wbf + 3 * WSZ;
    u16* WoB = wbf + 4 * WSZ;

    dim3 blk(256);
    cvt_kernel<<<dim3(320), blk, 0, stream>>>(Wp, Wq, Wk, Wv, Wo, wbf);
    ln_kernel<<<dim3(Tn / 32, Bn), blk, 0, stream>>>(x, xmask, gamma, beta, lnT);
    wp_kernel<<<dim3(Tn / 128, Cn / 64, Bn), blk, 0, stream>>>(
        lnT, WpB, bp, xmask, h1T);
    qkv_kernel<<<dim3(Tn / 128, Cn / 64, 3 * Bn), blk, 0, stream>>>(
        h1T, WqB, bq, WkB, bk, WvB, bv, xmask, qTt, kTt, vB);
    attn_kernel<<<dim3(256), dim3(512), 0, stream>>>(qTt, kTt, vB, xmask, PO, pL);
    final_kernel<<<dim3(Cn / 128, Tn / 64, Bn), blk, 0, stream>>>(
        WoB, bo, PO, pL, xmask, x, out);
}

// Round 9
// 277.895 us; speedup vs baseline: 1.5394x; 1.5394x over previous
//
#include <hip/hip_runtime.h>

#define Bn 4
#define Cn 256
#define Tn 4096

typedef unsigned short u16;
typedef __bf16 bf16x8 __attribute__((ext_vector_type(8)));
typedef float f32x4 __attribute__((ext_vector_type(4)));
typedef float f32x16 __attribute__((ext_vector_type(16)));
typedef u16 u16x8 __attribute__((ext_vector_type(8)));

__device__ __forceinline__ float b2f(u16 u) {
    union { unsigned int i; float f; } v;
    v.i = ((unsigned int)u) << 16;
    return v.f;
}
__device__ __forceinline__ u16 f2b(float f) {
    union { float f; unsigned int i; } v;
    v.f = f;
    unsigned int r = v.i + 0x7FFFu + ((v.i >> 16) & 1u);
    return (u16)(r >> 16);
}
__device__ __forceinline__ bf16x8 ones8() {
    union { u16 u[8]; bf16x8 v; } t;
    for (int j = 0; j < 8; j++) t.u[j] = 0x3F80;  // bf16 1.0
    return t.v;
}

// ---------------------------------------------------------------------------
// Weight convert: five fp32 [C][C] weights -> contiguous bf16 regions in ws.
// Region 1 (Wq) pre-scaled by 1/16 (attention scale folded into q-proj).
// ---------------------------------------------------------------------------
__global__ __launch_bounds__(256) void cvt_kernel(
    const float* __restrict__ w0, const float* __restrict__ w1,
    const float* __restrict__ w2, const float* __restrict__ w3,
    const float* __restrict__ w4, u16* __restrict__ dst)
{
    int gid = blockIdx.x * 256 + threadIdx.x;
    int base = gid * 4;
    int region = base >> 16;
    int off = base & 65535;
    const float* src = region == 0 ? w0 : region == 1 ? w1
                     : region == 2 ? w2 : region == 3 ? w3 : w4;
    float sc = (region == 1) ? 0.0625f : 1.0f;
    float4 v = *(const float4*)(src + off);
    ushort4 o;
    o.x = f2b(v.x * sc); o.y = f2b(v.y * sc);
    o.z = f2b(v.z * sc); o.w = f2b(v.w * sc);
    *(ushort4*)(dst + base) = o;
}

// ---------------------------------------------------------------------------
// LN: h = x*m (f32 stats), ln -> lnT [B][T][C] bf16. 32 t-rows/block.
// ---------------------------------------------------------------------------
__global__ __launch_bounds__(256) void ln_kernel(
    const float* __restrict__ x, const float* __restrict__ mask,
    const float* __restrict__ gamma, const float* __restrict__ beta,
    u16* __restrict__ lnT)
{
    __shared__ __attribute__((aligned(16))) u16 tile[32][264];
    __shared__ float ssum[8][32], ssq[8][32], smu[32], srs[32];
    const int tid = threadIdx.x;
    const int b = blockIdx.y;
    const int t0 = blockIdx.x * 32;
    const int g = tid >> 5, tl = tid & 31;
    const int t = t0 + tl;
    const float mval = mask[b * Tn + t];
    float s = 0.f, s2 = 0.f;
    for (int c = g; c < Cn; c += 8) {
        float v = x[((size_t)(b * Cn + c)) * Tn + t] * mval;
        s += v; s2 += v * v;
        tile[tl][c] = f2b(v);
    }
    ssum[g][tl] = s; ssq[g][tl] = s2;
    __syncthreads();
    if (tid < 32) {
        float su = 0.f, sq = 0.f;
        for (int k = 0; k < 8; k++) { su += ssum[k][tid]; sq += ssq[k][tid]; }
        float mu = su * (1.f / Cn);
        float var = sq * (1.f / Cn) - mu * mu;
        var = fmaxf(var, 0.0f);
        smu[tid] = mu;
        srs[tid] = 1.0f / sqrtf(var + 1e-5f);
    }
    __syncthreads();
    for (int it = 0; it < 4; it++) {
        int idx = it * 256 + tid;
        int row = idx >> 5, c16 = idx & 31;
        float mu = smu[row], rs = srs[row];
        u16x8 ov;
        for (int j = 0; j < 8; j++) {
            int c = c16 * 8 + j;
            float h = b2f(tile[row][c]);
            float v = (h - mu) * rs * gamma[c] + beta[c];
            ov[j] = f2b(v);
        }
        *(u16x8*)(lnT + ((size_t)(b * Tn + t0 + row)) * Cn + c16 * 8) = ov;
    }
}

// ---------------------------------------------------------------------------
// Wp GEMM: Y[t][o] = sum_c A[t][c]*W[o][c], (acc+bias)*mask -> bf16.
// ---------------------------------------------------------------------------
__global__ __launch_bounds__(256) void wp_kernel(
    const u16* __restrict__ Xb, const u16* __restrict__ Wb,
    const float* __restrict__ bias, const float* __restrict__ mask,
    u16* __restrict__ Yout)
{
    __shared__ __attribute__((aligned(16))) u16 Al[128][72];
    __shared__ __attribute__((aligned(16))) u16 Bl[64][72];
    const int tid = threadIdx.x;
    const int b = blockIdx.z;
    const int m0 = blockIdx.x * 128;
    const int n0 = blockIdx.y * 64;
    const int wave = tid >> 6, lane = tid & 63;
    const int ln16 = lane & 15, quad = lane >> 4;
    const int wm = (wave & 1) * 64, wn = (wave >> 1) * 32;

    const u16* Abase = Xb + ((size_t)(b * Tn + m0)) * Cn;
    const u16* Bbase = Wb + (size_t)n0 * Cn;

    f32x4 acc[4][2];
    for (int i = 0; i < 4; i++)
        for (int j = 0; j < 2; j++) acc[i][j] = (f32x4){0.f, 0.f, 0.f, 0.f};

    for (int k0 = 0; k0 < Cn; k0 += 64) {
        for (int it = 0; it < 4; it++) {
            int idx = it * 256 + tid;
            int row = idx >> 3, gg = idx & 7;
            *(uint4*)(&Al[row][gg * 8]) =
                *(const uint4*)(Abase + (size_t)row * Cn + k0 + gg * 8);
        }
        for (int it = 0; it < 2; it++) {
            int idx = it * 256 + tid;
            int row = idx >> 3, gg = idx & 7;
            *(uint4*)(&Bl[row][gg * 8]) =
                *(const uint4*)(Bbase + (size_t)row * Cn + k0 + gg * 8);
        }
        __syncthreads();
        for (int kk = 0; kk < 2; kk++) {
            bf16x8 af[4], bfr[2];
            for (int i = 0; i < 4; i++)
                af[i] = *(const bf16x8*)(&Al[wm + i * 16 + ln16][kk * 32 + quad * 8]);
            for (int j = 0; j < 2; j++)
                bfr[j] = *(const bf16x8*)(&Bl[wn + j * 16 + ln16][kk * 32 + quad * 8]);
            for (int i = 0; i < 4; i++)
                for (int j = 0; j < 2; j++)
                    acc[i][j] = __builtin_amdgcn_mfma_f32_16x16x32_bf16(
                        af[i], bfr[j], acc[i][j], 0, 0, 0);
        }
        __syncthreads();
    }
    for (int i = 0; i < 4; i++) {
        for (int j = 0; j < 2; j++) {
            int nn = n0 + wn + j * 16 + ln16;
            for (int r = 0; r < 4; r++) {
                int tt = m0 + wm + i * 16 + quad * 4 + r;
                float val = acc[i][j][r] + bias[nn];
                val *= mask[b * Tn + tt];
                Yout[((size_t)(b * Tn + tt)) * Cn + nn] = f2b(val);
            }
        }
    }
}

// ---------------------------------------------------------------------------
// Fused q/k/v projections. which=z>>2 (0=q,1=k,2=v), b=z&3. v: LDS-transpose
// epilogue for coalesced [C][T] store.
// ---------------------------------------------------------------------------
__global__ __launch_bounds__(256) void qkv_kernel(
    const u16* __restrict__ h1T,
    const u16* __restrict__ Wq_, const float* __restrict__ bq_,
    const u16* __restrict__ Wk_, const float* __restrict__ bk_,
    const u16* __restrict__ Wv_, const float* __restrict__ bv_,
    const float* __restrict__ mask,
    u16* __restrict__ qO, u16* __restrict__ kO, u16* __restrict__ vO)
{
    __shared__ __attribute__((aligned(16))) u16 Al[128][72];
    __shared__ __attribute__((aligned(16))) u16 Bl[64][72];
    const int tid = threadIdx.x;
    const int z = blockIdx.z;
    const int which = z >> 2;
    const int b = z & 3;
    const u16* W = which == 0 ? Wq_ : which == 1 ? Wk_ : Wv_;
    const float* bi = which == 0 ? bq_ : which == 1 ? bk_ : bv_;
    const float bsc = which == 0 ? 0.0625f : 1.0f;
    const int m0 = blockIdx.x * 128;   // t
    const int n0 = blockIdx.y * 64;    // o
    const int wave = tid >> 6, lane = tid & 63;
    const int ln16 = lane & 15, quad = lane >> 4;
    const int wm = (wave & 1) * 64, wn = (wave >> 1) * 32;

    const u16* Abase = h1T + ((size_t)(b * Tn + m0)) * Cn;
    const u16* Bbase = W + (size_t)n0 * Cn;

    f32x4 acc[4][2];
    for (int i = 0; i < 4; i++)
        for (int j = 0; j < 2; j++) acc[i][j] = (f32x4){0.f, 0.f, 0.f, 0.f};

    for (int k0 = 0; k0 < Cn; k0 += 64) {
        for (int it = 0; it < 4; it++) {
            int idx = it * 256 + tid;
            int row = idx >> 3, gg = idx & 7;
            *(uint4*)(&Al[row][gg * 8]) =
                *(const uint4*)(Abase + (size_t)row * Cn + k0 + gg * 8);
        }
        for (int it = 0; it < 2; it++) {
            int idx = it * 256 + tid;
            int row = idx >> 3, gg = idx & 7;
            *(uint4*)(&Bl[row][gg * 8]) =
                *(const uint4*)(Bbase + (size_t)row * Cn + k0 + gg * 8);
        }
        __syncthreads();
        for (int kk = 0; kk < 2; kk++) {
            bf16x8 af[4], bfr[2];
            for (int i = 0; i < 4; i++)
                af[i] = *(const bf16x8*)(&Al[wm + i * 16 + ln16][kk * 32 + quad * 8]);
            for (int j = 0; j < 2; j++)
                bfr[j] = *(const bf16x8*)(&Bl[wn + j * 16 + ln16][kk * 32 + quad * 8]);
            for (int i = 0; i < 4; i++)
                for (int j = 0; j < 2; j++)
                    acc[i][j] = __builtin_amdgcn_mfma_f32_16x16x32_bf16(
                        af[i], bfr[j], acc[i][j], 0, 0, 0);
        }
        __syncthreads();
    }

    if (which < 2) {
        u16* Yo = which == 0 ? qO : kO;
        for (int i = 0; i < 4; i++) {
            for (int j = 0; j < 2; j++) {
                int nn = n0 + wn + j * 16 + ln16;
                for (int r = 0; r < 4; r++) {
                    int tt = m0 + wm + i * 16 + quad * 4 + r;
                    float val = acc[i][j][r] + bi[nn] * bsc;
                    val *= mask[b * Tn + tt];
                    Yo[((size_t)(b * Tn + tt)) * Cn + nn] = f2b(val);
                }
            }
        }
    } else {
        u16* vt = &Al[0][0];
        for (int i = 0; i < 4; i++) {
            for (int j = 0; j < 2; j++) {
                int nl = wn + j * 16 + ln16;
                for (int r = 0; r < 4; r++) {
                    int ml = wm + i * 16 + quad * 4 + r;
                    int tt = m0 + ml;
                    float val = acc[i][j][r] + bi[n0 + nl];
                    val *= mask[b * Tn + tt];
                    vt[nl * 136 + ml] = f2b(val);
                }
            }
        }
        __syncthreads();
        for (int itc = 0; itc < 4; itc++) {
            int cidx = itc * 256 + tid;
            int row = cidx >> 4;
            int ch = cidx & 15;
            u16x8 ov = *(const u16x8*)(vt + row * 136 + ch * 8);
            *(u16x8*)(vO + ((size_t)(b * Cn + n0 + row)) * Tn + m0 + ch * 8) = ov;
        }
    }
}

// ---------------------------------------------------------------------------
// Flash attention (R6 structure: the measured-best 120 µs form). 512 thr =
// 8 waves; wave owns 32 q-rows; 32x32x16 MFMA; fixed-max softmax (q
// pre-scaled 1/16, M=8 in negk); l via MFMA vs ones; register prefetch.
// NEW: runtime s-split (4 or 8). split=8 -> 512 blocks = 2 blocks/CU =
// 4 waves/SIMD (R6 was grid 256 = 1 block/CU: pairing impossible by
// construction). Same-spl blocks share an XCD (id&7 round-robin) -> 2 MB
// K/V set per XCD L2. PO partial spl<2 overlays dead ws slots 0/1.
// ---------------------------------------------------------------------------
__global__ __launch_bounds__(512, 2) void attn_kernel(
    const u16* __restrict__ qT, const u16* __restrict__ kT,
    const u16* __restrict__ vv, const float* __restrict__ mask,
    u16* __restrict__ PO01, u16* __restrict__ POx, float* __restrict__ pL,
    int sshift)
{
    __shared__ __attribute__((aligned(16))) u16 kls[32][264];    // [s][c]
    __shared__ __attribute__((aligned(16))) u16 vls[256][40];    // [c][s]
    __shared__ __attribute__((aligned(16))) u16 pls[8][32][40];  // per-wave P
    __shared__ float nls[1024];
    const int tid = threadIdx.x;
    const int id = blockIdx.x;
    const int split = 1 << sshift;
    const int spl = id & (split - 1);
    const int b = (id >> sshift) & 3;
    const int qb = id >> (sshift + 2);
    const int t0 = qb * 256;
    const int wave = tid >> 6, lane = tid & 63;
    const int ln32 = lane & 31, half = lane >> 5;
    const int sLen = Tn >> sshift;
    const int sBeg = spl * sLen;
    const int nIter = sLen >> 5;

    for (int i = tid; i < sLen; i += 512)
        nls[i] = (1.0f - mask[b * Tn + sBeg + i]) * -1e8f - 8.0f;

    bf16x8 qf[16];
    {
        const u16* qp = qT + ((size_t)(b * Tn + t0 + wave * 32 + ln32)) * Cn + half * 8;
        for (int ks = 0; ks < 16; ks++) qf[ks] = *(const bf16x8*)(qp + ks * 16);
    }
    f32x16 acc[8], lac;
    for (int i = 0; i < 16; i++) lac[i] = 0.f;
    for (int nt = 0; nt < 8; nt++) acc[nt] = lac;
    const bf16x8 ones = ones8();

    uint4 kpre[2], vpre[2];
    auto loadK = [&](int s0) {
        for (int i = 0; i < 2; i++) {
            int idx = i * 512 + tid;
            kpre[i] = *(const uint4*)(kT + ((size_t)(b * Tn + s0 + (idx >> 5))) * Cn + (idx & 31) * 8);
        }
    };
    auto loadV = [&](int s0) {
        for (int i = 0; i < 2; i++) {
            int idx = i * 512 + tid;
            vpre[i] = *(const uint4*)(vv + ((size_t)(b * Cn + (idx >> 2))) * Tn + s0 + (idx & 3) * 8);
        }
    };
    loadK(sBeg);
    loadV(sBeg);

    for (int it = 0; it < nIter; it++) {
        const int s0 = sBeg + it * 32;
        __syncthreads();
        for (int i = 0; i < 2; i++) {
            int idx = i * 512 + tid;
            *(uint4*)(&kls[idx >> 5][(idx & 31) * 8]) = kpre[i];
        }
        for (int i = 0; i < 2; i++) {
            int idx = i * 512 + tid;
            *(uint4*)(&vls[idx >> 2][(idx & 3) * 8]) = vpre[i];
        }
        if (it + 1 < nIter) {
            loadK(s0 + 32);
            loadV(s0 + 32);
        }
        __syncthreads();
        const float negk = nls[it * 32 + ln32];

        f32x16 S;
        for (int i = 0; i < 16; i++) S[i] = 0.f;
        for (int ks = 0; ks < 16; ks++) {
            bf16x8 kf = *(const bf16x8*)(&kls[ln32][ks * 16 + half * 8]);
            S = __builtin_amdgcn_mfma_f32_32x32x16_bf16(qf[ks], kf, S, 0, 0, 0);
        }
        for (int r = 0; r < 16; r++) S[r] = __expf(S[r] + negk);
        for (int r = 0; r < 16; r++) {
            int row = (r & 3) + 8 * (r >> 2) + 4 * half;
            pls[wave][row][ln32] = f2b(S[r]);
        }
        bf16x8 pf0 = *(const bf16x8*)(&pls[wave][ln32][half * 8]);
        bf16x8 pf1 = *(const bf16x8*)(&pls[wave][ln32][16 + half * 8]);
        lac = __builtin_amdgcn_mfma_f32_32x32x16_bf16(pf0, ones, lac, 0, 0, 0);
        lac = __builtin_amdgcn_mfma_f32_32x32x16_bf16(pf1, ones, lac, 0, 0, 0);
        for (int nt = 0; nt < 8; nt++) {
            bf16x8 v0 = *(const bf16x8*)(&vls[nt * 32 + ln32][half * 8]);
            bf16x8 v1 = *(const bf16x8*)(&vls[nt * 32 + ln32][16 + half * 8]);
            acc[nt] = __builtin_amdgcn_mfma_f32_32x32x16_bf16(pf0, v0, acc[nt], 0, 0, 0);
            acc[nt] = __builtin_amdgcn_mfma_f32_32x32x16_bf16(pf1, v1, acc[nt], 0, 0, 0);
        }
    }
    const size_t SZe = (size_t)Bn * Tn * Cn;
    u16* myPO = (spl < 2) ? PO01 + (size_t)spl * SZe
                          : POx + (size_t)(spl - 2) * SZe;
    for (int r = 0; r < 16; r++) {
        int trow = (r & 3) + 8 * (r >> 2) + 4 * half;
        int t = t0 + wave * 32 + trow;
        for (int nt = 0; nt < 8; nt++)
            myPO[((size_t)(b * Tn + t)) * Cn + nt * 32 + ln32] = f2b(acc[nt][r]);
        if (ln32 == 0) pL[(size_t)spl * (Bn * Tn) + b * Tn + t] = lac[r];
    }
}

// ---------------------------------------------------------------------------
// Final GEMM with fused split-combine: B-staging sums `split` unnormalized
// PO partials; epilogue applies 1/sum(l), bias, residual, masks -> fp32.
// ---------------------------------------------------------------------------
__global__ __launch_bounds__(256) void final_kernel(
    const u16* __restrict__ WoB, const float* __restrict__ bo,
    const u16* __restrict__ PO01, const u16* __restrict__ POx,
    const float* __restrict__ pL,
    const float* __restrict__ mask, const float* __restrict__ x,
    float* __restrict__ out, int split)
{
    __shared__ __attribute__((aligned(16))) u16 Al[128][72];
    __shared__ __attribute__((aligned(16))) u16 Bl[64][72];
    __shared__ float rls[64];
    const int tid = threadIdx.x;
    const int b = blockIdx.z;
    const int m0 = blockIdx.x * 128;   // o
    const int n0 = blockIdx.y * 64;    // t
    const int wave = tid >> 6, lane = tid & 63;
    const int ln16 = lane & 15, quad = lane >> 4;
    const int wm = (wave & 1) * 64, wn = (wave >> 1) * 32;
    const size_t BT = (size_t)Bn * Tn;
    const size_t SZe = BT * Cn;

    if (tid < 64) {
        size_t R = (size_t)b * Tn + n0 + tid;
        float l = 0.f;
        for (int p = 0; p < split; p++) l += pL[p * BT + R];
        rls[tid] = 1.0f / fmaxf(l, 1e-30f);
    }

    f32x4 acc[4][2];
    for (int i = 0; i < 4; i++)
        for (int j = 0; j < 2; j++) acc[i][j] = (f32x4){0.f, 0.f, 0.f, 0.f};

    for (int k0 = 0; k0 < Cn; k0 += 64) {
        for (int it = 0; it < 4; it++) {
            int idx = it * 256 + tid;
            int row = idx >> 3, gg = idx & 7;
            *(uint4*)(&Al[row][gg * 8]) =
                *(const uint4*)(WoB + (size_t)(m0 + row) * Cn + k0 + gg * 8);
        }
        for (int it = 0; it < 2; it++) {
            int idx = it * 256 + tid;
            int row = idx >> 3, gg = idx & 7;
            size_t base = ((size_t)b * Tn + n0 + row) * Cn + k0 + gg * 8;
            float s8[8] = {0.f, 0.f, 0.f, 0.f, 0.f, 0.f, 0.f, 0.f};
            for (int p = 0; p < split; p++) {
                const u16* Pb = (p < 2) ? PO01 + (size_t)p * SZe
                                        : POx + (size_t)(p - 2) * SZe;
                u16x8 a = *(const u16x8*)(Pb + base);
                for (int j = 0; j < 8; j++) s8[j] += b2f(a[j]);
            }
            u16x8 o;
            for (int j = 0; j < 8; j++) o[j] = f2b(s8[j]);
            *(u16x8*)(&Bl[row][gg * 8]) = o;
        }
        __syncthreads();
        for (int kk = 0; kk < 2; kk++) {
            bf16x8 af[4], bfr[2];
            for (int i = 0; i < 4; i++)
                af[i] = *(const bf16x8*)(&Al[wm + i * 16 + ln16][kk * 32 + quad * 8]);
            for (int j = 0; j < 2; j++)
                bfr[j] = *(const bf16x8*)(&Bl[wn + j * 16 + ln16][kk * 32 + quad * 8]);
            for (int i = 0; i < 4; i++)
                for (int j = 0; j < 2; j++)
                    acc[i][j] = __builtin_amdgcn_mfma_f32_16x16x32_bf16(
                        af[i], bfr[j], acc[i][j], 0, 0, 0);
        }
        __syncthreads();
    }
    for (int i = 0; i < 4; i++) {
        for (int j = 0; j < 2; j++) {
            int nl = wn + j * 16 + ln16;
            int tt = n0 + nl;
            float rl = rls[nl];
            float mk = mask[b * Tn + tt];
            for (int r = 0; r < 4; r++) {
                int oo = m0 + wm + i * 16 + quad * 4 + r;
                float val = acc[i][j][r] * rl + bo[oo];
                float xr = x[((size_t)(b * Cn + oo)) * Tn + tt];
                out[((size_t)(b * Cn + oo)) * Tn + tt] = (xr + val * mk) * mk;
            }
        }
    }
}

extern "C" void kernel_launch(void* const* d_in, const int* in_sizes, int n_in,
                              void* d_out, int out_size, void* d_ws, size_t ws_size,
                              hipStream_t stream)
{
    const float* x     = (const float*)d_in[0];
    const float* xmask = (const float*)d_in[1];
    const float* gamma = (const float*)d_in[2];
    const float* beta  = (const float*)d_in[3];
    const float* Wp = (const float*)d_in[4];
    const float* bp = (const float*)d_in[5];
    const float* Wq = (const float*)d_in[6];
    const float* bq = (const float*)d_in[7];
    const float* Wk = (const float*)d_in[8];
    const float* bk = (const float*)d_in[9];
    const float* Wv = (const float*)d_in[10];
    const float* bv = (const float*)d_in[11];
    const float* Wo = (const float*)d_in[12];
    const float* bo = (const float*)d_in[13];
    float* out = (float*)d_out;

    u16* ws = (u16*)d_ws;
    const size_t SZ = (size_t)Bn * Tn * Cn;   // 4M elems
    const size_t WSZ = (size_t)Cn * Cn;
    const size_t BT = (size_t)Bn * Tn;
    u16* lnT = ws;            // slot0 [B][T][C]
    u16* h1T = ws + SZ;       // slot1
    u16* qTt = ws + 2 * SZ;
    u16* kTt = ws + 3 * SZ;
    u16* vB  = ws + 4 * SZ;   // [B][C][T]
    u16* wbf = ws + 5 * SZ;   // 5 bf16 weights
    u16* PO01 = ws;           // partials 0,1 overlay slots 0,1 (dead by attn)
    u16* POx  = ws + 5 * SZ + 5 * WSZ;   // partials 2..split-1

    u16* WpB = wbf;
    u16* WqB = wbf + WSZ;
    u16* WkB = wbf + 2 * WSZ;
    u16* WvB = wbf + 3 * WSZ;
    u16* WoB = wbf + 4 * WSZ;

    // choose split by workspace: split=8 needs 6 ext partials; fallback 4.
    auto need = [&](int split) {
        return (5 * SZ + 5 * WSZ + (size_t)(split - 2) * SZ) * 2
             + (size_t)split * BT * 4;
    };
    const int sshift = (ws_size >= need(8)) ? 3 : 2;
    const int split = 1 << sshift;
    float* pL = (float*)(POx + (size_t)(split - 2) * SZ);

    dim3 blk(256);
    cvt_kernel<<<dim3(320), blk, 0, stream>>>(Wp, Wq, Wk, Wv, Wo, wbf);
    ln_kernel<<<dim3(Tn / 32, Bn), blk, 0, stream>>>(x, xmask, gamma, beta, lnT);
    wp_kernel<<<dim3(Tn / 128, Cn / 64, Bn), blk, 0, stream>>>(
        lnT, WpB, bp, xmask, h1T);
    qkv_kernel<<<dim3(Tn / 128, Cn / 64, 3 * Bn), blk, 0, stream>>>(
        h1T, WqB, bq, WkB, bk, WvB, bv, xmask, qTt, kTt, vB);
    attn_kernel<<<dim3(64 * split), dim3(512), 0, stream>>>(
        qTt, kTt, vB, xmask, PO01, POx, pL, sshift);
    final_kernel<<<dim3(Cn / 128, Tn / 64, Bn), blk, 0, stream>>>(
        WoB, bo, PO01, POx, pL, xmask, x, out, split);
}

// Round 10
// 246.220 us; speedup vs baseline: 1.7375x; 1.1286x over previous
//
#include <hip/hip_runtime.h>

#define Bn 4
#define Cn 256
#define Tn 4096

typedef unsigned short u16;
typedef __bf16 bf16x8 __attribute__((ext_vector_type(8)));
typedef float f32x4 __attribute__((ext_vector_type(4)));
typedef float f32x16 __attribute__((ext_vector_type(16)));
typedef u16 u16x8 __attribute__((ext_vector_type(8)));

__device__ __forceinline__ float b2f(u16 u) {
    union { unsigned int i; float f; } v;
    v.i = ((unsigned int)u) << 16;
    return v.f;
}
__device__ __forceinline__ u16 f2b(float f) {
    union { float f; unsigned int i; } v;
    v.f = f;
    unsigned int r = v.i + 0x7FFFu + ((v.i >> 16) & 1u);
    return (u16)(r >> 16);
}
__device__ __forceinline__ bf16x8 ones8() {
    union { u16 u[8]; bf16x8 v; } t;
    for (int j = 0; j < 8; j++) t.u[j] = 0x3F80;  // bf16 1.0
    return t.v;
}

// ---------------------------------------------------------------------------
// Weight convert: five fp32 [C][C] weights -> contiguous bf16 regions in ws.
// Region 1 (Wq) pre-scaled by 1/16 (attention scale folded into q-proj).
// ---------------------------------------------------------------------------
__global__ __launch_bounds__(256) void cvt_kernel(
    const float* __restrict__ w0, const float* __restrict__ w1,
    const float* __restrict__ w2, const float* __restrict__ w3,
    const float* __restrict__ w4, u16* __restrict__ dst)
{
    int gid = blockIdx.x * 256 + threadIdx.x;
    int base = gid * 4;
    int region = base >> 16;
    int off = base & 65535;
    const float* src = region == 0 ? w0 : region == 1 ? w1
                     : region == 2 ? w2 : region == 3 ? w3 : w4;
    float sc = (region == 1) ? 0.0625f : 1.0f;
    float4 v = *(const float4*)(src + off);
    ushort4 o;
    o.x = f2b(v.x * sc); o.y = f2b(v.y * sc);
    o.z = f2b(v.z * sc); o.w = f2b(v.w * sc);
    *(ushort4*)(dst + base) = o;
}

// ---------------------------------------------------------------------------
// LN: h = x*m (f32 stats), ln -> lnT [B][T][C] bf16. Also emits xb = bf16
// masked-x in [B][C][T] for the final residual (mask is binary so
// (x + v*m)*m == (x*m + v)*m exactly). 32 t-rows/block.
// ---------------------------------------------------------------------------
__global__ __launch_bounds__(256) void ln_kernel(
    const float* __restrict__ x, const float* __restrict__ mask,
    const float* __restrict__ gamma, const float* __restrict__ beta,
    u16* __restrict__ lnT, u16* __restrict__ xb)
{
    __shared__ __attribute__((aligned(16))) u16 tile[32][264];
    __shared__ float ssum[8][32], ssq[8][32], smu[32], srs[32];
    const int tid = threadIdx.x;
    const int b = blockIdx.y;
    const int t0 = blockIdx.x * 32;
    const int g = tid >> 5, tl = tid & 31;
    const int t = t0 + tl;
    const float mval = mask[b * Tn + t];
    float s = 0.f, s2 = 0.f;
    for (int c = g; c < Cn; c += 8) {
        float v = x[((size_t)(b * Cn + c)) * Tn + t] * mval;
        s += v; s2 += v * v;
        u16 vb = f2b(v);
        tile[tl][c] = vb;
        xb[((size_t)(b * Cn + c)) * Tn + t] = vb;
    }
    ssum[g][tl] = s; ssq[g][tl] = s2;
    __syncthreads();
    if (tid < 32) {
        float su = 0.f, sq = 0.f;
        for (int k = 0; k < 8; k++) { su += ssum[k][tid]; sq += ssq[k][tid]; }
        float mu = su * (1.f / Cn);
        float var = sq * (1.f / Cn) - mu * mu;
        var = fmaxf(var, 0.0f);
        smu[tid] = mu;
        srs[tid] = 1.0f / sqrtf(var + 1e-5f);
    }
    __syncthreads();
    for (int it = 0; it < 4; it++) {
        int idx = it * 256 + tid;
        int row = idx >> 5, c16 = idx & 31;
        float mu = smu[row], rs = srs[row];
        u16x8 ov;
        for (int j = 0; j < 8; j++) {
            int c = c16 * 8 + j;
            float h = b2f(tile[row][c]);
            float v = (h - mu) * rs * gamma[c] + beta[c];
            ov[j] = f2b(v);
        }
        *(u16x8*)(lnT + ((size_t)(b * Tn + t0 + row)) * Cn + c16 * 8) = ov;
    }
}

// ---------------------------------------------------------------------------
// Wp GEMM: Y[t][o] = sum_c A[t][c]*W[o][c], (acc+bias)*mask -> bf16.
// ---------------------------------------------------------------------------
__global__ __launch_bounds__(256) void wp_kernel(
    const u16* __restrict__ Xb, const u16* __restrict__ Wb,
    const float* __restrict__ bias, const float* __restrict__ mask,
    u16* __restrict__ Yout)
{
    __shared__ __attribute__((aligned(16))) u16 Al[128][72];
    __shared__ __attribute__((aligned(16))) u16 Bl[64][72];
    const int tid = threadIdx.x;
    const int b = blockIdx.z;
    const int m0 = blockIdx.x * 128;
    const int n0 = blockIdx.y * 64;
    const int wave = tid >> 6, lane = tid & 63;
    const int ln16 = lane & 15, quad = lane >> 4;
    const int wm = (wave & 1) * 64, wn = (wave >> 1) * 32;

    const u16* Abase = Xb + ((size_t)(b * Tn + m0)) * Cn;
    const u16* Bbase = Wb + (size_t)n0 * Cn;

    f32x4 acc[4][2];
    for (int i = 0; i < 4; i++)
        for (int j = 0; j < 2; j++) acc[i][j] = (f32x4){0.f, 0.f, 0.f, 0.f};

    for (int k0 = 0; k0 < Cn; k0 += 64) {
        for (int it = 0; it < 4; it++) {
            int idx = it * 256 + tid;
            int row = idx >> 3, gg = idx & 7;
            *(uint4*)(&Al[row][gg * 8]) =
                *(const uint4*)(Abase + (size_t)row * Cn + k0 + gg * 8);
        }
        for (int it = 0; it < 2; it++) {
            int idx = it * 256 + tid;
            int row = idx >> 3, gg = idx & 7;
            *(uint4*)(&Bl[row][gg * 8]) =
                *(const uint4*)(Bbase + (size_t)row * Cn + k0 + gg * 8);
        }
        __syncthreads();
        for (int kk = 0; kk < 2; kk++) {
            bf16x8 af[4], bfr[2];
            for (int i = 0; i < 4; i++)
                af[i] = *(const bf16x8*)(&Al[wm + i * 16 + ln16][kk * 32 + quad * 8]);
            for (int j = 0; j < 2; j++)
                bfr[j] = *(const bf16x8*)(&Bl[wn + j * 16 + ln16][kk * 32 + quad * 8]);
            for (int i = 0; i < 4; i++)
                for (int j = 0; j < 2; j++)
                    acc[i][j] = __builtin_amdgcn_mfma_f32_16x16x32_bf16(
                        af[i], bfr[j], acc[i][j], 0, 0, 0);
        }
        __syncthreads();
    }
    for (int i = 0; i < 4; i++) {
        for (int j = 0; j < 2; j++) {
            int nn = n0 + wn + j * 16 + ln16;
            for (int r = 0; r < 4; r++) {
                int tt = m0 + wm + i * 16 + quad * 4 + r;
                float val = acc[i][j][r] + bias[nn];
                val *= mask[b * Tn + tt];
                Yout[((size_t)(b * Tn + tt)) * Cn + nn] = f2b(val);
            }
        }
    }
}

// ---------------------------------------------------------------------------
// Fused q/k/v projections. which=z>>2 (0=q,1=k,2=v), b=z&3. v: LDS-transpose
// epilogue for coalesced [C][T] store.
// ---------------------------------------------------------------------------
__global__ __launch_bounds__(256) void qkv_kernel(
    const u16* __restrict__ h1T,
    const u16* __restrict__ Wq_, const float* __restrict__ bq_,
    const u16* __restrict__ Wk_, const float* __restrict__ bk_,
    const u16* __restrict__ Wv_, const float* __restrict__ bv_,
    const float* __restrict__ mask,
    u16* __restrict__ qO, u16* __restrict__ kO, u16* __restrict__ vO)
{
    __shared__ __attribute__((aligned(16))) u16 Al[128][72];
    __shared__ __attribute__((aligned(16))) u16 Bl[64][72];
    const int tid = threadIdx.x;
    const int z = blockIdx.z;
    const int which = z >> 2;
    const int b = z & 3;
    const u16* W = which == 0 ? Wq_ : which == 1 ? Wk_ : Wv_;
    const float* bi = which == 0 ? bq_ : which == 1 ? bk_ : bv_;
    const float bsc = which == 0 ? 0.0625f : 1.0f;
    const int m0 = blockIdx.x * 128;   // t
    const int n0 = blockIdx.y * 64;    // o
    const int wave = tid >> 6, lane = tid & 63;
    const int ln16 = lane & 15, quad = lane >> 4;
    const int wm = (wave & 1) * 64, wn = (wave >> 1) * 32;

    const u16* Abase = h1T + ((size_t)(b * Tn + m0)) * Cn;
    const u16* Bbase = W + (size_t)n0 * Cn;

    f32x4 acc[4][2];
    for (int i = 0; i < 4; i++)
        for (int j = 0; j < 2; j++) acc[i][j] = (f32x4){0.f, 0.f, 0.f, 0.f};

    for (int k0 = 0; k0 < Cn; k0 += 64) {
        for (int it = 0; it < 4; it++) {
            int idx = it * 256 + tid;
            int row = idx >> 3, gg = idx & 7;
            *(uint4*)(&Al[row][gg * 8]) =
                *(const uint4*)(Abase + (size_t)row * Cn + k0 + gg * 8);
        }
        for (int it = 0; it < 2; it++) {
            int idx = it * 256 + tid;
            int row = idx >> 3, gg = idx & 7;
            *(uint4*)(&Bl[row][gg * 8]) =
                *(const uint4*)(Bbase + (size_t)row * Cn + k0 + gg * 8);
        }
        __syncthreads();
        for (int kk = 0; kk < 2; kk++) {
            bf16x8 af[4], bfr[2];
            for (int i = 0; i < 4; i++)
                af[i] = *(const bf16x8*)(&Al[wm + i * 16 + ln16][kk * 32 + quad * 8]);
            for (int j = 0; j < 2; j++)
                bfr[j] = *(const bf16x8*)(&Bl[wn + j * 16 + ln16][kk * 32 + quad * 8]);
            for (int i = 0; i < 4; i++)
                for (int j = 0; j < 2; j++)
                    acc[i][j] = __builtin_amdgcn_mfma_f32_16x16x32_bf16(
                        af[i], bfr[j], acc[i][j], 0, 0, 0);
        }
        __syncthreads();
    }

    if (which < 2) {
        u16* Yo = which == 0 ? qO : kO;
        for (int i = 0; i < 4; i++) {
            for (int j = 0; j < 2; j++) {
                int nn = n0 + wn + j * 16 + ln16;
                for (int r = 0; r < 4; r++) {
                    int tt = m0 + wm + i * 16 + quad * 4 + r;
                    float val = acc[i][j][r] + bi[nn] * bsc;
                    val *= mask[b * Tn + tt];
                    Yo[((size_t)(b * Tn + tt)) * Cn + nn] = f2b(val);
                }
            }
        }
    } else {
        u16* vt = &Al[0][0];
        for (int i = 0; i < 4; i++) {
            for (int j = 0; j < 2; j++) {
                int nl = wn + j * 16 + ln16;
                for (int r = 0; r < 4; r++) {
                    int ml = wm + i * 16 + quad * 4 + r;
                    int tt = m0 + ml;
                    float val = acc[i][j][r] + bi[n0 + nl];
                    val *= mask[b * Tn + tt];
                    vt[nl * 136 + ml] = f2b(val);
                }
            }
        }
        __syncthreads();
        for (int itc = 0; itc < 4; itc++) {
            int cidx = itc * 256 + tid;
            int row = cidx >> 4;
            int ch = cidx & 15;
            u16x8 ov = *(const u16x8*)(vt + row * 136 + ch * 8);
            *(u16x8*)(vO + ((size_t)(b * Cn + n0 + row)) * Tn + m0 + ch * 8) = ov;
        }
    }
}

// ---------------------------------------------------------------------------
// Flash attention. 512 thr = 8 waves; wave owns 32 q-rows; 32x32x16 MFMA;
// fixed-max softmax (q pre-scaled 1/16, M=8 in negk); l via MFMA vs ones;
// register prefetch. split=4 (grid 256 = 1 block/CU, the measured residency).
// R10: kls/vls DOUBLE-BUFFERED -> ONE barrier per iteration (buffer N's
// reads drain at the intervening iteration's barrier before N is rewritten;
// pls is per-wave, in-order DS needs no barrier). Registers unchanged vs R6
// (the spill cliff sits right above R6's 128 VGPR — R8 lesson).
// ---------------------------------------------------------------------------
__global__ __launch_bounds__(512, 2) void attn_kernel(
    const u16* __restrict__ qT, const u16* __restrict__ kT,
    const u16* __restrict__ vv, const float* __restrict__ mask,
    u16* __restrict__ PO01, u16* __restrict__ POx, float* __restrict__ pL)
{
    __shared__ __attribute__((aligned(16))) u16 kls[2][32][264];   // [s][c] x2
    __shared__ __attribute__((aligned(16))) u16 vls[2][256][40];   // [c][s] x2
    __shared__ __attribute__((aligned(16))) u16 pls[8][32][40];    // per-wave P
    __shared__ float nls[1024];
    const int tid = threadIdx.x;
    const int id = blockIdx.x;
    const int spl = id & 3;
    const int b = (id >> 2) & 3;
    const int qb = id >> 4;
    const int t0 = qb * 256;
    const int wave = tid >> 6, lane = tid & 63;
    const int ln32 = lane & 31, half = lane >> 5;
    const int sBeg = spl * (Tn / 4);
    const int nIter = (Tn / 4) / 32;        // 32

    for (int i = tid; i < 1024; i += 512)
        nls[i] = (1.0f - mask[b * Tn + sBeg + i]) * -1e8f - 8.0f;

    bf16x8 qf[16];
    {
        const u16* qp = qT + ((size_t)(b * Tn + t0 + wave * 32 + ln32)) * Cn + half * 8;
        for (int ks = 0; ks < 16; ks++) qf[ks] = *(const bf16x8*)(qp + ks * 16);
    }
    f32x16 acc[8], lac;
    for (int i = 0; i < 16; i++) lac[i] = 0.f;
    for (int nt = 0; nt < 8; nt++) acc[nt] = lac;
    const bf16x8 ones = ones8();

    uint4 kpre[2], vpre[2];
    auto loadK = [&](int s0) {
        for (int i = 0; i < 2; i++) {
            int idx = i * 512 + tid;
            kpre[i] = *(const uint4*)(kT + ((size_t)(b * Tn + s0 + (idx >> 5))) * Cn + (idx & 31) * 8);
        }
    };
    auto loadV = [&](int s0) {
        for (int i = 0; i < 2; i++) {
            int idx = i * 512 + tid;
            vpre[i] = *(const uint4*)(vv + ((size_t)(b * Cn + (idx >> 2))) * Tn + s0 + (idx & 3) * 8);
        }
    };
    loadK(sBeg);
    loadV(sBeg);

    for (int it = 0; it < nIter; it++) {
        const int s0 = sBeg + it * 32;
        const int cb = it & 1;
        // stage current tile into buffer cb (no pre-barrier: cb's previous
        // readers drained at the previous iteration's barrier)
        for (int i = 0; i < 2; i++) {
            int idx = i * 512 + tid;
            *(uint4*)(&kls[cb][idx >> 5][(idx & 31) * 8]) = kpre[i];
        }
        for (int i = 0; i < 2; i++) {
            int idx = i * 512 + tid;
            *(uint4*)(&vls[cb][idx >> 2][(idx & 3) * 8]) = vpre[i];
        }
        if (it + 1 < nIter) {
            loadK(s0 + 32);
            loadV(s0 + 32);
        }
        __syncthreads();                    // publish buffer cb
        const float negk = nls[it * 32 + ln32];

        f32x16 S;
        for (int i = 0; i < 16; i++) S[i] = 0.f;
        for (int ks = 0; ks < 16; ks++) {
            bf16x8 kf = *(const bf16x8*)(&kls[cb][ln32][ks * 16 + half * 8]);
            S = __builtin_amdgcn_mfma_f32_32x32x16_bf16(qf[ks], kf, S, 0, 0, 0);
        }
        for (int r = 0; r < 16; r++) S[r] = __expf(S[r] + negk);
        for (int r = 0; r < 16; r++) {
            int row = (r & 3) + 8 * (r >> 2) + 4 * half;
            pls[wave][row][ln32] = f2b(S[r]);
        }
        bf16x8 pf0 = *(const bf16x8*)(&pls[wave][ln32][half * 8]);
        bf16x8 pf1 = *(const bf16x8*)(&pls[wave][ln32][16 + half * 8]);
        lac = __builtin_amdgcn_mfma_f32_32x32x16_bf16(pf0, ones, lac, 0, 0, 0);
        lac = __builtin_amdgcn_mfma_f32_32x32x16_bf16(pf1, ones, lac, 0, 0, 0);
        for (int nt = 0; nt < 8; nt++) {
            bf16x8 v0 = *(const bf16x8*)(&vls[cb][nt * 32 + ln32][half * 8]);
            bf16x8 v1 = *(const bf16x8*)(&vls[cb][nt * 32 + ln32][16 + half * 8]);
            acc[nt] = __builtin_amdgcn_mfma_f32_32x32x16_bf16(pf0, v0, acc[nt], 0, 0, 0);
            acc[nt] = __builtin_amdgcn_mfma_f32_32x32x16_bf16(pf1, v1, acc[nt], 0, 0, 0);
        }
    }
    const size_t SZe = (size_t)Bn * Tn * Cn;
    u16* myPO = (spl < 2) ? PO01 + (size_t)spl * SZe
                          : POx + (size_t)(spl - 2) * SZe;
    for (int r = 0; r < 16; r++) {
        int trow = (r & 3) + 8 * (r >> 2) + 4 * half;
        int t = t0 + wave * 32 + trow;
        for (int nt = 0; nt < 8; nt++)
            myPO[((size_t)(b * Tn + t)) * Cn + nt * 32 + ln32] = f2b(acc[nt][r]);
        if (ln32 == 0) pL[(size_t)spl * (Bn * Tn) + b * Tn + t] = lac[r];
    }
}

// ---------------------------------------------------------------------------
// Final GEMM with fused split-combine: B-staging sums 4 unnormalized PO
// partials; epilogue applies 1/sum(l), bias, bf16 residual (xb), mask -> f32.
// (mask binary: (x + v*m)*m == (x*m + v)*m; xb stores x*m in bf16.)
// ---------------------------------------------------------------------------
__global__ __launch_bounds__(256) void final_kernel(
    const u16* __restrict__ WoB, const float* __restrict__ bo,
    const u16* __restrict__ PO01, const u16* __restrict__ POx,
    const float* __restrict__ pL,
    const float* __restrict__ mask, const u16* __restrict__ xb,
    float* __restrict__ out)
{
    __shared__ __attribute__((aligned(16))) u16 Al[128][72];
    __shared__ __attribute__((aligned(16))) u16 Bl[64][72];
    __shared__ float rls[64];
    const int tid = threadIdx.x;
    const int b = blockIdx.z;
    const int m0 = blockIdx.x * 128;   // o
    const int n0 = blockIdx.y * 64;    // t
    const int wave = tid >> 6, lane = tid & 63;
    const int ln16 = lane & 15, quad = lane >> 4;
    const int wm = (wave & 1) * 64, wn = (wave >> 1) * 32;
    const size_t BT = (size_t)Bn * Tn;
    const size_t SZe = BT * Cn;

    if (tid < 64) {
        size_t R = (size_t)b * Tn + n0 + tid;
        float l = pL[R] + pL[BT + R] + pL[2 * BT + R] + pL[3 * BT + R];
        rls[tid] = 1.0f / fmaxf(l, 1e-30f);
    }

    f32x4 acc[4][2];
    for (int i = 0; i < 4; i++)
        for (int j = 0; j < 2; j++) acc[i][j] = (f32x4){0.f, 0.f, 0.f, 0.f};

    for (int k0 = 0; k0 < Cn; k0 += 64) {
        for (int it = 0; it < 4; it++) {
            int idx = it * 256 + tid;
            int row = idx >> 3, gg = idx & 7;
            *(uint4*)(&Al[row][gg * 8]) =
                *(const uint4*)(WoB + (size_t)(m0 + row) * Cn + k0 + gg * 8);
        }
        for (int it = 0; it < 2; it++) {
            int idx = it * 256 + tid;
            int row = idx >> 3, gg = idx & 7;
            size_t base = ((size_t)b * Tn + n0 + row) * Cn + k0 + gg * 8;
            u16x8 a0 = *(const u16x8*)(PO01 + base);
            u16x8 a1 = *(const u16x8*)(PO01 + SZe + base);
            u16x8 a2 = *(const u16x8*)(POx + base);
            u16x8 a3 = *(const u16x8*)(POx + SZe + base);
            u16x8 o;
            for (int j = 0; j < 8; j++)
                o[j] = f2b(b2f(a0[j]) + b2f(a1[j]) + b2f(a2[j]) + b2f(a3[j]));
            *(u16x8*)(&Bl[row][gg * 8]) = o;
        }
        __syncthreads();
        for (int kk = 0; kk < 2; kk++) {
            bf16x8 af[4], bfr[2];
            for (int i = 0; i < 4; i++)
                af[i] = *(const bf16x8*)(&Al[wm + i * 16 + ln16][kk * 32 + quad * 8]);
            for (int j = 0; j < 2; j++)
                bfr[j] = *(const bf16x8*)(&Bl[wn + j * 16 + ln16][kk * 32 + quad * 8]);
            for (int i = 0; i < 4; i++)
                for (int j = 0; j < 2; j++)
                    acc[i][j] = __builtin_amdgcn_mfma_f32_16x16x32_bf16(
                        af[i], bfr[j], acc[i][j], 0, 0, 0);
        }
        __syncthreads();
    }
    for (int i = 0; i < 4; i++) {
        for (int j = 0; j < 2; j++) {
            int nl = wn + j * 16 + ln16;
            int tt = n0 + nl;
            float rl = rls[nl];
            float mk = mask[b * Tn + tt];
            for (int r = 0; r < 4; r++) {
                int oo = m0 + wm + i * 16 + quad * 4 + r;
                float val = acc[i][j][r] * rl + bo[oo];
                float xr = b2f(xb[((size_t)(b * Cn + oo)) * Tn + tt]);
                out[((size_t)(b * Cn + oo)) * Tn + tt] = (xr + val) * mk;
            }
        }
    }
}

extern "C" void kernel_launch(void* const* d_in, const int* in_sizes, int n_in,
                              void* d_out, int out_size, void* d_ws, size_t ws_size,
                              hipStream_t stream)
{
    const float* x     = (const float*)d_in[0];
    const float* xmask = (const float*)d_in[1];
    const float* gamma = (const float*)d_in[2];
    const float* beta  = (const float*)d_in[3];
    const float* Wp = (const float*)d_in[4];
    const float* bp = (const float*)d_in[5];
    const float* Wq = (const float*)d_in[6];
    const float* bq = (const float*)d_in[7];
    const float* Wk = (const float*)d_in[8];
    const float* bk = (const float*)d_in[9];
    const float* Wv = (const float*)d_in[10];
    const float* bv = (const float*)d_in[11];
    const float* Wo = (const float*)d_in[12];
    const float* bo = (const float*)d_in[13];
    float* out = (float*)d_out;

    u16* ws = (u16*)d_ws;
    const size_t SZ = (size_t)Bn * Tn * Cn;   // 4M elems
    const size_t WSZ = (size_t)Cn * Cn;
    const size_t BT = (size_t)Bn * Tn;
    u16* lnT = ws;            // slot0 [B][T][C]
    u16* h1T = ws + SZ;       // slot1
    u16* qTt = ws + 2 * SZ;
    u16* kTt = ws + 3 * SZ;
    u16* vB  = ws + 4 * SZ;   // [B][C][T]
    u16* wbf = ws + 5 * SZ;   // 5 bf16 weights
    u16* PO01 = ws;           // partials 0,1 overlay slots 0,1 (dead by attn)
    u16* POx  = ws + 5 * SZ + 5 * WSZ;   // partials 2,3
    float* pL = (float*)(POx + 2 * SZ);  // 4 x [B*T] f32
    u16* xb   = (u16*)(pL + 4 * BT);     // bf16 masked-x [B][C][T]

    u16* WpB = wbf;
    u16* WqB = wbf + WSZ;
    u16* WkB = wbf + 2 * WSZ;
    u16* WvB = wbf + 3 * WSZ;
    u16* WoB = wbf + 4 * WSZ;

    dim3 blk(256);
    cvt_kernel<<<dim3(320), blk, 0, stream>>>(Wp, Wq, Wk, Wv, Wo, wbf);
    ln_kernel<<<dim3(Tn / 32, Bn), blk, 0, stream>>>(x, xmask, gamma, beta, lnT, xb);
    wp_kernel<<<dim3(Tn / 128, Cn / 64, Bn), blk, 0, stream>>>(
        lnT, WpB, bp, xmask, h1T);
    qkv_kernel<<<dim3(Tn / 128, Cn / 64, 3 * Bn), blk, 0, stream>>>(
        h1T, WqB, bq, WkB, bk, WvB, bv, xmask, qTt, kTt, vB);
    attn_kernel<<<dim3(256), dim3(512), 0, stream>>>(
        qTt, kTt, vB, xmask, PO01, POx, pL);
    final_kernel<<<dim3(Cn / 128, Tn / 64, Bn), blk, 0, stream>>>(
        WoB, bo, PO01, POx, pL, xmask, xb, out);
}